// Round 12
// baseline (182.381 us; speedup 1.0000x reference)
//
#include <hip/hip_runtime.h>
#include <cmath>

// Problem constants (fixed by reference file)
#define B_     8
#define NH_    32
#define HD_    128
#define HID_   4096
#define MAXS_  4096
#define NPAIR_ (B_ * NH_)          // 256 (b,h) pairs
#define NSPLIT_ 4                  // key-splits per pair
#define PSTR_  132                 // partial stride: m, l, pad, pad, acc[128]
#define QS_    (3 * B_ * HID_)     // qkv partial stride (one K-half)
#define NEG_BIG_ (-1e30f)

typedef float f4_ __attribute__((ext_vector_type(4)));

__device__ __forceinline__ f4_ ntload4(const float* p) {
  return __builtin_nontemporal_load((const f4_*)p);
}
__device__ __forceinline__ f4_ ld4(const float* p) {
  return *(const f4_*)p;
}
__device__ __forceinline__ float dot4(f4_ a, f4_ b) {
  f4_ m = a * b;
  return m.x + m.y + m.z + m.w;
}

// K-split TA-efficient GEMV: 1 wave (64 thr) per block, 8 rows, NSL K-slices
// of 256. Partial sums to out + ks*part_stride. 8w+8x loads per slice keeps
// weights at 50% of VMEM-port bytes (round-11 win); register-double-buffered
// weights with x-first-then-w issue order (vmcnt is in-order; round-10
// lesson); #pragma unroll 1 (round-10 VGPR pathology). K-split raises
// resident waves/CU: at ~180 VGPR the allocator rounds to the 256 step ->
// 8 waves/CU cap (m68/m69); wo was dispatching only 2 (round-11 limiter).
// Weights NORMAL loads (L3-resident across replays; nt KV can't evict).
template<int NSL>
__global__ __launch_bounds__(64) void gemv_ks(
    const float* __restrict__ W0, const float* __restrict__ W1,
    const float* __restrict__ W2, const float* __restrict__ x,
    float* __restrict__ out, int nb_per_mat, int n_inner, int part_stride)
{
  const int bid   = blockIdx.x;
  const int ks    = bid / n_inner;          // K-split index
  const int inner = bid % n_inner;
  const int m     = inner / nb_per_mat;     // matrix index (0..2)
  const int r0    = (inner % nb_per_mat) * 8;
  const float* __restrict__ W = (m == 0) ? W0 : ((m == 1) ? W1 : W2);
  float* o = out + (size_t)ks * part_stride + m * (B_ * HID_);

  const int lane = threadIdx.x;             // 0..63
  const int kofs = ks * NSL * 256;          // this block's K-range start

  float acc[8][8];
#pragma unroll
  for (int r = 0; r < 8; ++r)
#pragma unroll
    for (int b = 0; b < 8; ++b) acc[r][b] = 0.f;

  const float* Wp = W + (size_t)r0 * HID_ + kofs + lane * 4;
  const float* xp = x + kofs + lane * 4;

  f4_ wa[8], wb[8];
#pragma unroll
  for (int r = 0; r < 8; ++r) wa[r] = ld4(Wp + (size_t)r * HID_);

#pragma unroll 1
  for (int u = 0; u < NSL; u += 2) {
    // ---- phase A: compute slice u from wa; prefetch u+1 into wb ----
    {
      const int j = u * 256;
      f4_ xv[8];
#pragma unroll
      for (int b = 0; b < 8; ++b) xv[b] = ld4(xp + b * HID_ + j);
#pragma unroll
      for (int r = 0; r < 8; ++r)
        wb[r] = ld4(Wp + (size_t)r * HID_ + j + 256);
#pragma unroll
      for (int r = 0; r < 8; ++r)
#pragma unroll
        for (int b = 0; b < 8; ++b) acc[r][b] += dot4(wa[r], xv[b]);
    }
    // ---- phase B: compute slice u+1 from wb; prefetch u+2 into wa ----
    {
      const int j = (u + 1) * 256;
      f4_ xv[8];
#pragma unroll
      for (int b = 0; b < 8; ++b) xv[b] = ld4(xp + b * HID_ + j);
      if (u + 2 < NSL) {
#pragma unroll
        for (int r = 0; r < 8; ++r)
          wa[r] = ld4(Wp + (size_t)r * HID_ + j + 256);
      }
#pragma unroll
      for (int r = 0; r < 8; ++r)
#pragma unroll
        for (int b = 0; b < 8; ++b) acc[r][b] += dot4(wb[r], xv[b]);
    }
  }

  // butterfly reduce each of the 64 partials across the wave
#pragma unroll
  for (int r = 0; r < 8; ++r)
#pragma unroll
    for (int b = 0; b < 8; ++b) {
      float v = acc[r][b];
#pragma unroll
      for (int off = 32; off; off >>= 1) v += __shfl_xor(v, off);
      acc[r][b] = v;
    }

  if (lane == 0) {
#pragma unroll
    for (int r = 0; r < 8; ++r)
#pragma unroll
      for (int b = 0; b < 8; ++b)
        o[(size_t)b * HID_ + r0 + r] = acc[r][b];
  }
}

// out[i] = sum of 4 K-split partials (deterministic, no atomics).
__global__ __launch_bounds__(256) void sum4(
    const float* __restrict__ part, float* __restrict__ out)
{
  const int gid = blockIdx.x * 256 + threadIdx.x;   // 8192 f4 elements
  const int i = gid * 4;
  f4_ v = ld4(part + i) + ld4(part + (B_ * HID_) + i)
        + ld4(part + 2 * (B_ * HID_) + i) + ld4(part + 3 * (B_ * HID_) + i);
  *(f4_*)(out + i) = v;
}

// Flash-decoding partials: 4 blocks (256 thr = 4 waves) per (b,h) pair.
// q/k/v-fresh are the SUM of the two QKV K-split halves (qkv, qkv+QS_).
// K/V rows nt (stream-once; must not evict L3-resident weights).
__global__ __launch_bounds__(256, 4) void attn_partial(
    const float* __restrict__ qkv, const float* __restrict__ ck,
    const float* __restrict__ cv, const int* __restrict__ ppos,
    float* __restrict__ part)
{
  __shared__ float sm[4], sl[4];
  __shared__ float sacc[4][HD_];

  const int pos  = *ppos;
  const int bid  = blockIdx.x;
  const int pair = bid >> 2;
  const int s    = bid & (NSPLIT_ - 1);
  const int b    = pair >> 5;
  const int h    = pair & (NH_ - 1);
  const int w    = threadIdx.x >> 6;
  const int lane = threadIdx.x & 63;
  const int half = lane >> 5, l32 = lane & 31;
  const int k0   = s * 512 + w * 128;

  float m = NEG_BIG_, l = 0.f;
  f4_ acc = (f4_)0.f;

  if (k0 <= pos) {
    const float scale = 0.08838834764831845f;   // 1/sqrt(128)
    const int hoff = b * HID_ + h * HD_ + l32 * 4;
    f4_ q4  = (ld4(qkv + hoff) + ld4(qkv + QS_ + hoff)) * scale;
    f4_ kf4 =  ld4(qkv + B_ * HID_ + hoff) + ld4(qkv + QS_ + B_ * HID_ + hoff);
    f4_ vf4 =  ld4(qkv + 2 * B_ * HID_ + hoff) + ld4(qkv + QS_ + 2 * B_ * HID_ + hoff);
    const float* ckh = ck + ((size_t)(b * NH_ + h)) * MAXS_ * HD_;
    const float* cvh = cv + ((size_t)(b * NH_ + h)) * MAXS_ * HD_;

    for (int c = 0; c < 8; ++c) {
      const int kbase = k0 + c * 16;
      f4_ k4[8], v4[8];
#pragma unroll
      for (int j = 0; j < 8; ++j) {
        const int ki = kbase + 2 * j + half;
        k4[j] = ntload4(ckh + (size_t)ki * HD_ + l32 * 4);
        v4[j] = ntload4(cvh + (size_t)ki * HD_ + l32 * 4);
      }
      // fresh-token overwrite (ki==pos row of the cache is stale)
#pragma unroll
      for (int j = 0; j < 8; ++j) {
        const int ki = kbase + 2 * j + half;
        if (ki == pos) { k4[j] = kf4; v4[j] = vf4; }
      }

      float sc[8];
#pragma unroll
      for (int j = 0; j < 8; ++j) sc[j] = dot4(q4, k4[j]);

#pragma unroll
      for (int off = 16; off >= 1; off >>= 1)
#pragma unroll
        for (int j = 0; j < 8; ++j) sc[j] += __shfl_xor(sc[j], off);

#pragma unroll
      for (int j = 0; j < 8; ++j) {
        const int ki = kbase + 2 * j + half;
        if (ki > pos) sc[j] = -INFINITY;
      }

      const float cm = fmaxf(fmaxf(fmaxf(sc[0], sc[1]), fmaxf(sc[2], sc[3])),
                             fmaxf(fmaxf(sc[4], sc[5]), fmaxf(sc[6], sc[7])));
      const float mn   = fmaxf(m, cm);
      const float corr = __expf(m - mn);
      float p[8], ps = 0.f;
#pragma unroll
      for (int j = 0; j < 8; ++j) { p[j] = __expf(sc[j] - mn); ps += p[j]; }
      l = l * corr + ps;
      acc *= corr;
#pragma unroll
      for (int j = 0; j < 8; ++j) acc += p[j] * v4[j];
      m = mn;
    }
  }

  const float mo = __shfl_xor(m, 32);
  const float lo = __shfl_xor(l, 32);
  f4_ ao;
  ao.x = __shfl_xor(acc.x, 32); ao.y = __shfl_xor(acc.y, 32);
  ao.z = __shfl_xor(acc.z, 32); ao.w = __shfl_xor(acc.w, 32);
  const float mm = fmaxf(m, mo);
  const float w0 = __expf(m - mm), w1 = __expf(mo - mm);
  const float lm = l * w0 + lo * w1;
  f4_ am = acc * w0 + ao * w1;

  if (half == 0) {
    *(f4_*)&sacc[w][l32 * 4] = am;
    if (l32 == 0) { sm[w] = mm; sl[w] = lm; }
  }
  __syncthreads();

  if (threadIdx.x < 32) {
    const int t = threadIdx.x;
    float mg = NEG_BIG_;
#pragma unroll
    for (int u = 0; u < 4; ++u)
      if (sl[u] > 0.f) mg = fmaxf(mg, sm[u]);
    float ls = 0.f;
    f4_ o = (f4_)0.f;
#pragma unroll
    for (int u = 0; u < 4; ++u)
      if (sl[u] > 0.f) {
        const float wu = __expf(sm[u] - mg);
        ls += sl[u] * wu;
        o  += wu * ld4(&sacc[u][t * 4]);
      }
    float* pb = part + (size_t)bid * PSTR_;
    *(f4_*)(pb + 4 + t * 4) = o;
    if (t == 0) { pb[0] = (ls > 0.f) ? mg : NEG_BIG_; pb[1] = ls; }
  }
}

// Merge the 4 split partials per (b,h) into attn output [b][h*128+d].
__global__ __launch_bounds__(128) void attn_combine(
    const float* __restrict__ part, float* __restrict__ attnout)
{
  const int pair = blockIdx.x;
  const int d    = threadIdx.x;
  const float* pb = part + (size_t)pair * NSPLIT_ * PSTR_;

  float mg = NEG_BIG_;
#pragma unroll
  for (int u = 0; u < NSPLIT_; ++u) {
    const float lu = pb[u * PSTR_ + 1];
    if (lu > 0.f) mg = fmaxf(mg, pb[u * PSTR_]);
  }
  float ls = 0.f, o = 0.f;
#pragma unroll
  for (int u = 0; u < NSPLIT_; ++u) {
    const float lu = pb[u * PSTR_ + 1];
    if (lu > 0.f) {
      const float wu = __expf(pb[u * PSTR_] - mg);
      ls += lu * wu;
      o  += wu * pb[u * PSTR_ + 4 + d];
    }
  }
  attnout[pair * HD_ + d] = o / ls;
}

extern "C" void kernel_launch(void* const* d_in, const int* in_sizes, int n_in,
                              void* d_out, int out_size, void* d_ws, size_t ws_size,
                              hipStream_t stream) {
  const float* x  = (const float*)d_in[0];
  const float* ck = (const float*)d_in[1];
  const float* cv = (const float*)d_in[2];
  const float* wq = (const float*)d_in[3];
  const float* wk = (const float*)d_in[4];
  const float* wv = (const float*)d_in[5];
  const float* wo = (const float*)d_in[6];
  const int* pos  = (const int*)d_in[7];
  float* out = (float*)d_out;
  float* ws  = (float*)d_ws;

  float* qkvp    = ws;                                   // 2 * QS_ floats
  float* part    = qkvp + 2 * QS_;                       // 1024 * 132
  float* attnout = part + NPAIR_ * NSPLIT_ * PSTR_;      // B*HID
  float* wopart  = attnout + B_ * HID_;                  // 4 * B*HID

  // QKV: K-split x2 -> 3072 one-wave blocks (8/CU resident + refill)
  gemv_ks<8><<<2 * 3 * 512, 64, 0, stream>>>(wq, wk, wv, x, qkvp,
                                             512, 3 * 512, QS_);
  attn_partial<<<NPAIR_ * NSPLIT_, 256, 0, stream>>>(qkvp, ck, cv, pos, part);
  attn_combine<<<NPAIR_, 128, 0, stream>>>(part, attnout);
  // wo: K-split x4 -> 2048 one-wave blocks (8/CU), then deterministic sum
  gemv_ks<4><<<4 * 512, 64, 0, stream>>>(wo, wo, wo, attnout, wopart,
                                         512, 512, B_ * HID_);
  sum4<<<(B_ * HID_) / (256 * 4), 256, 0, stream>>>(wopart, out);
}

// Round 13
// 176.528 us; speedup vs baseline: 1.0332x; 1.0332x over previous
//
#include <hip/hip_runtime.h>
#include <cmath>

// Problem constants (fixed by reference file)
#define B_     8
#define NH_    32
#define HD_    128
#define HID_   4096
#define MAXS_  4096
#define NPAIR_ (B_ * NH_)          // 256 (b,h) pairs
#define NSPLIT_ 4                  // key-splits per pair
#define PSTR_  132                 // partial stride: m, l, pad, pad, acc[128]
#define NEG_BIG_ (-1e30f)

typedef float f4_ __attribute__((ext_vector_type(4)));

__device__ __forceinline__ f4_ ntload4(const float* p) {
  return __builtin_nontemporal_load((const f4_*)p);
}
__device__ __forceinline__ f4_ ld4(const float* p) {
  return *(const f4_*)p;
}
__device__ __forceinline__ float dot4(f4_ a, f4_ b) {
  f4_ m = a * b;
  return m.x + m.y + m.z + m.w;
}

// Fully software-pipelined GEMV: 1 wave/block, 8 rows, NSL K-slices of 256.
// BOTH w and x are register-prefetched ONE FULL SLICE ahead (4 named buffers,
// static indices): every load is issued ~512cy+16 issue-slots before first
// use, covering L3 weight latency AND the L1/L2 x latency that round-11's
// same-phase x-issue left exposed. #pragma unroll 1 (round-10 VGPR lesson);
// in-order vmcnt respected (loads of phase N+1 issued before compute N's
// successors wait on them). 8w+8x per slice keeps weights at 50% of VMEM
// bytes (round-11 win). Weights NORMAL loads (L3-resident across replays;
// nt KV can't evict them). K-split via ks for occupancy (wo: 512 blocks
// = 2/CU was latency-starved).
template<int NSL>
__global__ __launch_bounds__(64) void gemv8p(
    const float* __restrict__ W0, const float* __restrict__ W1,
    const float* __restrict__ W2, const float* __restrict__ x,
    float* __restrict__ out, int nb_per_mat, int n_inner, int part_stride)
{
  const int bid   = blockIdx.x;
  const int ks    = bid / n_inner;          // K-split index
  const int inner = bid % n_inner;
  const int m     = inner / nb_per_mat;     // matrix index (0..2)
  const int r0    = (inner % nb_per_mat) * 8;
  const float* __restrict__ W = (m == 0) ? W0 : ((m == 1) ? W1 : W2);
  float* o = out + (size_t)ks * part_stride + m * (B_ * HID_);

  const int lane = threadIdx.x;             // 0..63
  const int kofs = ks * NSL * 256;

  float acc[8][8];
#pragma unroll
  for (int r = 0; r < 8; ++r)
#pragma unroll
    for (int b = 0; b < 8; ++b) acc[r][b] = 0.f;

  const float* Wp = W + (size_t)r0 * HID_ + kofs + lane * 4;
  const float* xp = x + kofs + lane * 4;

  f4_ wa[8], wb[8], xa[8], xb[8];
  // prologue: slice 0 into (wa, xa)
#pragma unroll
  for (int r = 0; r < 8; ++r) wa[r] = ld4(Wp + (size_t)r * HID_);
#pragma unroll
  for (int b = 0; b < 8; ++b) xa[b] = ld4(xp + b * HID_);

#pragma unroll 1
  for (int u = 0; u < NSL; u += 2) {
    // ---- phase A: prefetch slice u+1 into (wb,xb); compute slice u ----
    {
      const int j1 = (u + 1) * 256;
#pragma unroll
      for (int r = 0; r < 8; ++r) wb[r] = ld4(Wp + (size_t)r * HID_ + j1);
#pragma unroll
      for (int b = 0; b < 8; ++b) xb[b] = ld4(xp + b * HID_ + j1);
#pragma unroll
      for (int r = 0; r < 8; ++r)
#pragma unroll
        for (int b = 0; b < 8; ++b) acc[r][b] += dot4(wa[r], xa[b]);
    }
    // ---- phase B: prefetch slice u+2 into (wa,xa); compute slice u+1 ----
    {
      if (u + 2 < NSL) {
        const int j2 = (u + 2) * 256;
#pragma unroll
        for (int r = 0; r < 8; ++r) wa[r] = ld4(Wp + (size_t)r * HID_ + j2);
#pragma unroll
        for (int b = 0; b < 8; ++b) xa[b] = ld4(xp + b * HID_ + j2);
      }
#pragma unroll
      for (int r = 0; r < 8; ++r)
#pragma unroll
        for (int b = 0; b < 8; ++b) acc[r][b] += dot4(wb[r], xb[b]);
    }
  }

  // butterfly reduce each of the 64 partials across the wave
#pragma unroll
  for (int r = 0; r < 8; ++r)
#pragma unroll
    for (int b = 0; b < 8; ++b) {
      float v = acc[r][b];
#pragma unroll
      for (int off = 32; off; off >>= 1) v += __shfl_xor(v, off);
      acc[r][b] = v;
    }

  if (lane == 0) {
#pragma unroll
    for (int r = 0; r < 8; ++r)
#pragma unroll
      for (int b = 0; b < 8; ++b)
        o[(size_t)b * HID_ + r0 + r] = acc[r][b];
  }
}

// out[i] = sum of 4 K-split partials (deterministic, no atomics).
__global__ __launch_bounds__(256) void sum4(
    const float* __restrict__ part, float* __restrict__ out)
{
  const int gid = blockIdx.x * 256 + threadIdx.x;   // 8192 f4 elements
  const int i = gid * 4;
  f4_ v = ld4(part + i) + ld4(part + (B_ * HID_) + i)
        + ld4(part + 2 * (B_ * HID_) + i) + ld4(part + 3 * (B_ * HID_) + i);
  *(f4_*)(out + i) = v;
}

// Flash-decoding partials: 4 blocks (256 thr = 4 waves) per (b,h) pair.
// K/V rows nt (stream-once; must not evict L3-resident weights).
// Fresh-token rows overwritten from workspace (inputs never mutated).
__global__ __launch_bounds__(256, 4) void attn_partial(
    const float* __restrict__ qkv, const float* __restrict__ ck,
    const float* __restrict__ cv, const int* __restrict__ ppos,
    float* __restrict__ part)
{
  __shared__ float sm[4], sl[4];
  __shared__ float sacc[4][HD_];

  const int pos  = *ppos;
  const int bid  = blockIdx.x;
  const int pair = bid >> 2;
  const int s    = bid & (NSPLIT_ - 1);
  const int b    = pair >> 5;
  const int h    = pair & (NH_ - 1);
  const int w    = threadIdx.x >> 6;
  const int lane = threadIdx.x & 63;
  const int half = lane >> 5, l32 = lane & 31;
  const int k0   = s * 512 + w * 128;

  float m = NEG_BIG_, l = 0.f;
  f4_ acc = (f4_)0.f;

  if (k0 <= pos) {
    const float scale = 0.08838834764831845f;   // 1/sqrt(128)
    const int hoff = b * HID_ + h * HD_ + l32 * 4;
    f4_ q4  = ld4(qkv + hoff) * scale;
    f4_ kf4 = ld4(qkv + B_ * HID_ + hoff);
    f4_ vf4 = ld4(qkv + 2 * B_ * HID_ + hoff);
    const float* ckh = ck + ((size_t)(b * NH_ + h)) * MAXS_ * HD_;
    const float* cvh = cv + ((size_t)(b * NH_ + h)) * MAXS_ * HD_;

    for (int c = 0; c < 8; ++c) {
      const int kbase = k0 + c * 16;
      f4_ k4[8], v4[8];
#pragma unroll
      for (int j = 0; j < 8; ++j) {
        const int ki = kbase + 2 * j + half;
        k4[j] = ntload4(ckh + (size_t)ki * HD_ + l32 * 4);
        v4[j] = ntload4(cvh + (size_t)ki * HD_ + l32 * 4);
      }
      // fresh-token overwrite (ki==pos row of the cache is stale)
#pragma unroll
      for (int j = 0; j < 8; ++j) {
        const int ki = kbase + 2 * j + half;
        if (ki == pos) { k4[j] = kf4; v4[j] = vf4; }
      }

      float sc[8];
#pragma unroll
      for (int j = 0; j < 8; ++j) sc[j] = dot4(q4, k4[j]);

#pragma unroll
      for (int off = 16; off >= 1; off >>= 1)
#pragma unroll
        for (int j = 0; j < 8; ++j) sc[j] += __shfl_xor(sc[j], off);

#pragma unroll
      for (int j = 0; j < 8; ++j) {
        const int ki = kbase + 2 * j + half;
        if (ki > pos) sc[j] = -INFINITY;
      }

      const float cm = fmaxf(fmaxf(fmaxf(sc[0], sc[1]), fmaxf(sc[2], sc[3])),
                             fmaxf(fmaxf(sc[4], sc[5]), fmaxf(sc[6], sc[7])));
      const float mn   = fmaxf(m, cm);
      const float corr = __expf(m - mn);
      float p[8], ps = 0.f;
#pragma unroll
      for (int j = 0; j < 8; ++j) { p[j] = __expf(sc[j] - mn); ps += p[j]; }
      l = l * corr + ps;
      acc *= corr;
#pragma unroll
      for (int j = 0; j < 8; ++j) acc += p[j] * v4[j];
      m = mn;
    }
  }

  const float mo = __shfl_xor(m, 32);
  const float lo = __shfl_xor(l, 32);
  f4_ ao;
  ao.x = __shfl_xor(acc.x, 32); ao.y = __shfl_xor(acc.y, 32);
  ao.z = __shfl_xor(acc.z, 32); ao.w = __shfl_xor(acc.w, 32);
  const float mm = fmaxf(m, mo);
  const float w0 = __expf(m - mm), w1 = __expf(mo - mm);
  const float lm = l * w0 + lo * w1;
  f4_ am = acc * w0 + ao * w1;

  if (half == 0) {
    *(f4_*)&sacc[w][l32 * 4] = am;
    if (l32 == 0) { sm[w] = mm; sl[w] = lm; }
  }
  __syncthreads();

  if (threadIdx.x < 32) {
    const int t = threadIdx.x;
    float mg = NEG_BIG_;
#pragma unroll
    for (int u = 0; u < 4; ++u)
      if (sl[u] > 0.f) mg = fmaxf(mg, sm[u]);
    float ls = 0.f;
    f4_ o = (f4_)0.f;
#pragma unroll
    for (int u = 0; u < 4; ++u)
      if (sl[u] > 0.f) {
        const float wu = __expf(sm[u] - mg);
        ls += sl[u] * wu;
        o  += wu * ld4(&sacc[u][t * 4]);
      }
    float* pb = part + (size_t)bid * PSTR_;
    *(f4_*)(pb + 4 + t * 4) = o;
    if (t == 0) { pb[0] = (ls > 0.f) ? mg : NEG_BIG_; pb[1] = ls; }
  }
}

// Merge the 4 split partials per (b,h) into attn output [b][h*128+d].
__global__ __launch_bounds__(128) void attn_combine(
    const float* __restrict__ part, float* __restrict__ attnout)
{
  const int pair = blockIdx.x;
  const int d    = threadIdx.x;
  const float* pb = part + (size_t)pair * NSPLIT_ * PSTR_;

  float mg = NEG_BIG_;
#pragma unroll
  for (int u = 0; u < NSPLIT_; ++u) {
    const float lu = pb[u * PSTR_ + 1];
    if (lu > 0.f) mg = fmaxf(mg, pb[u * PSTR_]);
  }
  float ls = 0.f, o = 0.f;
#pragma unroll
  for (int u = 0; u < NSPLIT_; ++u) {
    const float lu = pb[u * PSTR_ + 1];
    if (lu > 0.f) {
      const float wu = __expf(pb[u * PSTR_] - mg);
      ls += lu * wu;
      o  += wu * pb[u * PSTR_ + 4 + d];
    }
  }
  attnout[pair * HD_ + d] = o / ls;
}

extern "C" void kernel_launch(void* const* d_in, const int* in_sizes, int n_in,
                              void* d_out, int out_size, void* d_ws, size_t ws_size,
                              hipStream_t stream) {
  const float* x  = (const float*)d_in[0];
  const float* ck = (const float*)d_in[1];
  const float* cv = (const float*)d_in[2];
  const float* wq = (const float*)d_in[3];
  const float* wk = (const float*)d_in[4];
  const float* wv = (const float*)d_in[5];
  const float* wo = (const float*)d_in[6];
  const int* pos  = (const int*)d_in[7];
  float* out = (float*)d_out;
  float* ws  = (float*)d_ws;

  float* qkv     = ws;                                   // 3*8*4096 floats
  float* part    = qkv + 3 * B_ * HID_;                  // 1024 * 132
  float* attnout = part + NPAIR_ * NSPLIT_ * PSTR_;      // B*HID
  float* wopart  = attnout + B_ * HID_;                  // 4 * B*HID

  // QKV: no K-split (1536 one-wave blocks; round-12 split was neutral)
  gemv8p<16><<<3 * 512, 64, 0, stream>>>(wq, wk, wv, x, qkv,
                                         512, 3 * 512, 0);
  attn_partial<<<NPAIR_ * NSPLIT_, 256, 0, stream>>>(qkv, ck, cv, pos, part);
  attn_combine<<<NPAIR_, 128, 0, stream>>>(part, attnout);
  // wo: K-split x4 (2048 blocks -> 8/CU; 512 blocks = 2/CU was starved)
  gemv8p<4><<<4 * 512, 64, 0, stream>>>(wo, wo, wo, attnout, wopart,
                                        512, 512, B_ * HID_);
  sum4<<<(B_ * HID_) / (256 * 4), 256, 0, stream>>>(wopart, out);
}